// Round 20
// baseline (313.244 us; speedup 1.0000x reference)
//
#include <hip/hip_runtime.h>
#include <hip/hip_fp16.h>

#define N_NODES  50000
#define N_EDGES  640000
#define N_GRAPHS 500
static constexpr float BN_EPS = 1e-5f;
#define SCAN_NB ((N_NODES + 255) / 256)   // 196 blocks
static constexpr float FIX = 16777216.0f;       // 2^24
static constexpr float FIXINV = 5.9604644775390625e-8f;  // 2^-24
static constexpr float Q16 = 65535.0f;
static constexpr float Q16INV = 1.0f / 65535.0f;

// csr entry: (src<<16) | round(norm*65535). src<50000<2^16; norm<1.
__device__ __forceinline__ float dec_nm(unsigned e) {
    return (float)(e & 0xFFFFu) * Q16INV;
}

// ---------------------------------------------------------------------------
// Packed degree/count: one 64-bit atomic per edge; old value -> seq[] rank.
__global__ void k_degcnt(const int* __restrict__ dst, const float* __restrict__ w,
                         unsigned long long* __restrict__ packed,
                         int* __restrict__ seq, int E) {
    int i = blockIdx.x * blockDim.x + threadIdx.x;
    if (i < E) {
        int d = dst[i];
        unsigned uf = (unsigned)(w[i] * FIX + 0.5f);
        unsigned long long old =
            atomicAdd(&packed[d], (1ULL << 32) | (unsigned long long)uf);
        seq[i] = (int)(old >> 32);
    }
}

// --- 3-phase hierarchical exclusive scan of counts (packed hi32) -> offs ---
__global__ void k_scan1(const unsigned long long* __restrict__ packed,
                        int* __restrict__ bsum, int n) {
    __shared__ int red[256];
    int i = blockIdx.x * 256 + threadIdx.x;
    red[threadIdx.x] = (i < n) ? (int)(packed[i] >> 32) : 0;
    __syncthreads();
    for (int off = 128; off > 0; off >>= 1) {
        if (threadIdx.x < off) red[threadIdx.x] += red[threadIdx.x + off];
        __syncthreads();
    }
    if (threadIdx.x == 0) bsum[blockIdx.x] = red[0];
}

__global__ void k_scan2(const int* __restrict__ bsum, int* __restrict__ bpre, int nb) {
    __shared__ int part[256];
    int t = threadIdx.x;
    part[t] = (t < nb) ? bsum[t] : 0;
    __syncthreads();
    for (int off = 1; off < 256; off <<= 1) {
        int v = (t >= off) ? part[t - off] : 0;
        __syncthreads();
        part[t] += v;
        __syncthreads();
    }
    if (t < nb) bpre[t] = (t == 0) ? 0 : part[t - 1];
}

// scan3 + dinv fused (same N-grid).
__global__ void k_scan3(const unsigned long long* __restrict__ packed,
                        const int* __restrict__ bpre, int* __restrict__ offs,
                        float* __restrict__ dinv, int n) {
    __shared__ int part[256];
    int i = blockIdx.x * 256 + threadIdx.x;
    int t = threadIdx.x;
    unsigned long long pk = (i < n) ? packed[i] : 0ULL;
    int v = (int)(pk >> 32);
    part[t] = v;
    __syncthreads();
    for (int off = 1; off < 256; off <<= 1) {
        int u = (t >= off) ? part[t - off] : 0;
        __syncthreads();
        part[t] += u;
        __syncthreads();
    }
    int excl = bpre[blockIdx.x] + part[t] - v;
    if (i < n) {
        offs[i] = excl;
        float wdeg = (float)(unsigned)(pk & 0xFFFFFFFFu) * FIXINV;
        dinv[i] = rsqrtf(wdeg + 1.0f);
    }
    if (i == n - 1) offs[n] = N_EDGES;
}

// Atomic-free CSR fill: pos = offs[dst] + seq[e]. 4-byte packed entry.
__global__ void k_fill(const int* __restrict__ src, const int* __restrict__ dst,
                       const float* __restrict__ w, const float* __restrict__ dinv,
                       const int* __restrict__ offs, const int* __restrict__ seq,
                       unsigned* __restrict__ csr, int E) {
    int e = blockIdx.x * blockDim.x + threadIdx.x;
    if (e < E) {
        int s = src[e], d = dst[e];
        int pos = offs[d] + seq[e];
        float nm = dinv[s] * w[e] * dinv[d];
        unsigned q = (unsigned)(nm * Q16 + 0.5f);
        q = (q > 65535u) ? 65535u : q;
        csr[pos] = ((unsigned)s << 16) | q;
    }
}

// Fold bias+BN into per-channel affine. Layer1 additionally folds W1 (rank-1).
__global__ void k_bnprep_all(
    const float* W1,
    const float* b1, const float* g1, const float* be1, const float* m1, const float* v1,
    const float* b2, const float* g2, const float* be2, const float* m2, const float* v2,
    const float* b3, const float* g3, const float* be3, const float* m3, const float* v3,
    float* kA1, float* kB1, float* kA2, float* kB2, float* kA3, float* kB3) {
    int t = threadIdx.x;
    if (t < 64) {
        float s = g1[t] * rsqrtf(v1[t] + BN_EPS);
        kA1[t] = W1[t] * s;
        kB1[t] = (b1[t] - m1[t]) * s + be1[t];
    } else if (t < 192) {
        int c = t - 64;
        float s = g2[c] * rsqrtf(v2[c] + BN_EPS);
        kA2[c] = s; kB2[c] = (b2[c] - m2[c]) * s + be2[c];
    } else if (t < 320) {
        int c = t - 192;
        float s = g3[c] * rsqrtf(v3[c] + BN_EPS);
        kA3[c] = s; kB3[c] = (b3[c] - m3[c]) * s + be3[c];
    }
}

// Layer-1 scalar aggregation (id order; 4-edge unrolled).
__global__ void k_aggx(const int* __restrict__ offs, const unsigned* __restrict__ csr,
                       const float* __restrict__ x, const float* __restrict__ dinv,
                       float* __restrict__ aggx, int n) {
    int i = blockIdx.x * blockDim.x + threadIdx.x;
    if (i >= n) return;
    float acc = 0.f;
    int e0 = offs[i], e1 = offs[i + 1];
    int j = e0;
    for (; j + 3 < e1; j += 4) {
        unsigned ea = csr[j];
        unsigned eb = csr[j + 1];
        unsigned ec = csr[j + 2];
        unsigned ed = csr[j + 3];
        acc += x[ea >> 16] * dec_nm(ea) + x[eb >> 16] * dec_nm(eb)
             + x[ec >> 16] * dec_nm(ec) + x[ed >> 16] * dec_nm(ed);
    }
    for (; j < e1; ++j) {
        unsigned e = csr[j];
        acc += x[e >> 16] * dec_nm(e);
    }
    float di = dinv[i];
    aggx[i] = acc + x[i] * di * di;
}

// ---------------------------------------------------------------------------
// Fused layer-1-matmul + layer-2 aggregation. 16 threads/node, 4 ch each.
__global__ void k_gather2F(const int* __restrict__ offs, const unsigned* __restrict__ csr,
                           const float* __restrict__ aggx, const float* __restrict__ dinv,
                           const float* __restrict__ kA1, const float* __restrict__ kB1,
                           float* __restrict__ agg2, int n) {
    int gid = blockIdx.x * blockDim.x + threadIdx.x;
    int node = gid >> 4;
    if (node >= n) return;
    int c4 = (gid & 15) * 4;
    float4 wa = *(const float4*)(kA1 + c4);
    float4 wb = *(const float4*)(kB1 + c4);
    float4 acc = {0.f, 0.f, 0.f, 0.f};
    int e0 = offs[node], e1 = offs[node + 1];
    int j = e0;
    for (; j + 3 < e1; j += 4) {
        unsigned ea = csr[j];
        unsigned eb = csr[j + 1];
        unsigned ec = csr[j + 2];
        unsigned ed = csr[j + 3];
        float aa = aggx[ea >> 16];
        float ab = aggx[eb >> 16];
        float ac = aggx[ec >> 16];
        float ad = aggx[ed >> 16];
        float nma = dec_nm(ea);
        float nmb = dec_nm(eb);
        float nmc = dec_nm(ec);
        float nmd = dec_nm(ed);
        acc.x += nma * fmaxf(aa * wa.x + wb.x, 0.f) + nmb * fmaxf(ab * wa.x + wb.x, 0.f)
               + nmc * fmaxf(ac * wa.x + wb.x, 0.f) + nmd * fmaxf(ad * wa.x + wb.x, 0.f);
        acc.y += nma * fmaxf(aa * wa.y + wb.y, 0.f) + nmb * fmaxf(ab * wa.y + wb.y, 0.f)
               + nmc * fmaxf(ac * wa.y + wb.y, 0.f) + nmd * fmaxf(ad * wa.y + wb.y, 0.f);
        acc.z += nma * fmaxf(aa * wa.z + wb.z, 0.f) + nmb * fmaxf(ab * wa.z + wb.z, 0.f)
               + nmc * fmaxf(ac * wa.z + wb.z, 0.f) + nmd * fmaxf(ad * wa.z + wb.z, 0.f);
        acc.w += nma * fmaxf(aa * wa.w + wb.w, 0.f) + nmb * fmaxf(ab * wa.w + wb.w, 0.f)
               + nmc * fmaxf(ac * wa.w + wb.w, 0.f) + nmd * fmaxf(ad * wa.w + wb.w, 0.f);
    }
    for (; j < e1; ++j) {
        unsigned e = csr[j];
        float a = aggx[e >> 16];
        float nm = dec_nm(e);
        acc.x += nm * fmaxf(a * wa.x + wb.x, 0.f);
        acc.y += nm * fmaxf(a * wa.y + wb.y, 0.f);
        acc.z += nm * fmaxf(a * wa.z + wb.z, 0.f);
        acc.w += nm * fmaxf(a * wa.w + wb.w, 0.f);
    }
    float di = dinv[node];
    float d2 = di * di;
    float a = aggx[node];
    acc.x += d2 * fmaxf(a * wa.x + wb.x, 0.f);
    acc.y += d2 * fmaxf(a * wa.y + wb.y, 0.f);
    acc.z += d2 * fmaxf(a * wa.z + wb.z, 0.f);
    acc.w += d2 * fmaxf(a * wa.w + wb.w, 0.f);
    *(float4*)(agg2 + (size_t)node * 64 + c4) = acc;
}

// ---------------------------------------------------------------------------
// Channel-sliced gather (layer 3) from the FP16 layer-2 output.
// 4 slices x 32 fp16 channels: row = 64B = one full fetch line (r20 lever —
// sliced-16 fp16 rows were 32B, wasting half of every gathered line).
// 8 thr/node x 8B covers the row cooperatively; csr re-read 4x (was 8x).
// fp32 accumulation; 8-edge unroll.
__global__ void k_gatherS16(const int* __restrict__ offs, const unsigned* __restrict__ csr,
                            const __half* __restrict__ Hh, const float* __restrict__ dinv,
                            float* __restrict__ aggs, int n) {
    int slice = blockIdx.x & 3;
    int node = (blockIdx.x >> 2) * 32 + threadIdx.x / 8;
    if (node >= n) return;
    int cq = (threadIdx.x % 8) * 4;          // fp16 channel offset within slice
    const __half* Hb = Hh + (size_t)slice * ((size_t)n * 32);
    float4 acc = {0.f, 0.f, 0.f, 0.f};
    int e0 = offs[node], e1 = offs[node + 1];
    int j = e0;
#define GS16_LOAD(ev, rawv) uint2 rawv = *(const uint2*)(Hb + (size_t)((ev) >> 16) * 32 + cq)
#define GS16_ACC(rawv, nmv) { \
        __half2 p0 = *(__half2*)&rawv.x; \
        __half2 p1 = *(__half2*)&rawv.y; \
        float2 f0 = __half22float2(p0); \
        float2 f1 = __half22float2(p1); \
        acc.x += f0.x * nmv; acc.y += f0.y * nmv; \
        acc.z += f1.x * nmv; acc.w += f1.y * nmv; }
    for (; j + 7 < e1; j += 8) {
        unsigned e_0 = csr[j];
        unsigned e_1 = csr[j + 1];
        unsigned e_2 = csr[j + 2];
        unsigned e_3 = csr[j + 3];
        unsigned e_4 = csr[j + 4];
        unsigned e_5 = csr[j + 5];
        unsigned e_6 = csr[j + 6];
        unsigned e_7 = csr[j + 7];
        GS16_LOAD(e_0, r0); GS16_LOAD(e_1, r1); GS16_LOAD(e_2, r2); GS16_LOAD(e_3, r3);
        GS16_LOAD(e_4, r4); GS16_LOAD(e_5, r5); GS16_LOAD(e_6, r6); GS16_LOAD(e_7, r7);
        GS16_ACC(r0, dec_nm(e_0)); GS16_ACC(r1, dec_nm(e_1));
        GS16_ACC(r2, dec_nm(e_2)); GS16_ACC(r3, dec_nm(e_3));
        GS16_ACC(r4, dec_nm(e_4)); GS16_ACC(r5, dec_nm(e_5));
        GS16_ACC(r6, dec_nm(e_6)); GS16_ACC(r7, dec_nm(e_7));
    }
    for (; j < e1; ++j) {
        unsigned e = csr[j];
        GS16_LOAD(e, rr);
        GS16_ACC(rr, dec_nm(e));
    }
    {
        float di = dinv[node];
        float d2 = di * di;
        GS16_LOAD((unsigned)node << 16, rs);
        GS16_ACC(rs, d2);
    }
#undef GS16_LOAD
#undef GS16_ACC
    *(float4*)(aggs + (size_t)slice * ((size_t)n * 32) + (size_t)node * 32 + cq) = acc;
}

// ---------------------------------------------------------------------------
// Register-tiled matmul: 32 nodes/block, x-tile AND W staged in LDS.
// k4/p loops pinned rolled (#pragma unroll 1) — r6/r8 spilled at 256 VGPR.
// Sliced-32 slot layout: slot = (c>>5)*(n*32) + node*32 + (c&31).
// MODE 0 (layer 2): write fp16 table only.
// MODE 1 (layer 3): residual from fp16 table; write fp32 IN-PLACE into Xs.
template <int K, int S, int MODE>
__global__ __launch_bounds__(256) void k_mmT(
    const float* __restrict__ Xs, const float* __restrict__ W,
    const float* __restrict__ kA, const float* __restrict__ kB,
    const __half* __restrict__ resh, float* __restrict__ outs,
    __half* __restrict__ outh, int n) {
    constexpr int CS = K / S;
    constexpr int KP = K + 4;
    constexpr int KH = 64;
    constexpr int NPASS = K / KH;
    __shared__ float xl[32 * KP];
    __shared__ float wl[KH * 128];
    int base = blockIdx.x * 32;
    int tid = threadIdx.x;
    constexpr int TOT4 = 32 * K / 4;
    constexpr int SL4 = 32 * CS / 4;
    for (int i = tid; i < TOT4; i += 256) {
        int slice = i / SL4;
        int rem = i - slice * SL4;
        int nl = rem / (CS / 4);
        int off4 = (rem % (CS / 4)) * 4;
        int node = base + nl;
        float4 v = {0.f, 0.f, 0.f, 0.f};
        if (node < n)
            v = *(const float4*)(Xs + (size_t)slice * ((size_t)n * CS) + (size_t)node * CS + off4);
        *(float4*)(&xl[nl * KP + slice * CS + off4]) = v;
    }

    int ct = tid & 31;
    int ng = tid >> 5;
    int c4 = ct * 4;
    float4 acc[4];
#pragma unroll
    for (int i = 0; i < 4; ++i) acc[i] = make_float4(0.f, 0.f, 0.f, 0.f);

#pragma unroll 1
    for (int p = 0; p < NPASS; ++p) {
        if (p > 0) __syncthreads();
        {
            const float4* Wsrc = (const float4*)(W + (size_t)p * KH * 128);
            float4* wl4 = (float4*)wl;
#pragma unroll 1
            for (int i = tid; i < KH * 32; i += 256) wl4[i] = Wsrc[i];
        }
        __syncthreads();

#pragma unroll 1
        for (int k4 = 0; k4 < KH / 4; ++k4) {
            float4 wv0 = *(const float4*)(&wl[(k4 * 4 + 0) * 128 + c4]);
            float4 wv1 = *(const float4*)(&wl[(k4 * 4 + 1) * 128 + c4]);
            float4 wv2 = *(const float4*)(&wl[(k4 * 4 + 2) * 128 + c4]);
            float4 wv3 = *(const float4*)(&wl[(k4 * 4 + 3) * 128 + c4]);
#pragma unroll
            for (int i = 0; i < 4; ++i) {
                float4 xv = *(const float4*)(&xl[(ng * 4 + i) * KP + p * KH + k4 * 4]);
                acc[i].x += xv.x * wv0.x; acc[i].y += xv.x * wv0.y;
                acc[i].z += xv.x * wv0.z; acc[i].w += xv.x * wv0.w;
                acc[i].x += xv.y * wv1.x; acc[i].y += xv.y * wv1.y;
                acc[i].z += xv.y * wv1.z; acc[i].w += xv.y * wv1.w;
                acc[i].x += xv.z * wv2.x; acc[i].y += xv.z * wv2.y;
                acc[i].z += xv.z * wv2.z; acc[i].w += xv.z * wv2.w;
                acc[i].x += xv.w * wv3.x; acc[i].y += xv.w * wv3.y;
                acc[i].z += xv.w * wv3.z; acc[i].w += xv.w * wv3.w;
            }
        }
    }

    float4 ka = *(const float4*)(kA + c4);
    float4 kb = *(const float4*)(kB + c4);
#pragma unroll
    for (int i = 0; i < 4; ++i) {
        int node = base + ng * 4 + i;
        if (node >= n) continue;
        float4 a = acc[i];
        float4 v;
        v.x = fmaxf(a.x * ka.x + kb.x, 0.f);
        v.y = fmaxf(a.y * ka.y + kb.y, 0.f);
        v.z = fmaxf(a.z * ka.z + kb.z, 0.f);
        v.w = fmaxf(a.w * ka.w + kb.w, 0.f);
        size_t slot = (size_t)(c4 >> 5) * ((size_t)n * 32) + (size_t)node * 32 + (c4 & 31);
        if (MODE == 0) {
            __half2 h01 = __floats2half2_rn(v.x, v.y);
            __half2 h23 = __floats2half2_rn(v.z, v.w);
            uint2 r;
            r.x = *(unsigned*)&h01;
            r.y = *(unsigned*)&h23;
            *(uint2*)(outh + slot) = r;
        } else {
            uint2 rr = *(const uint2*)(resh + slot);
            __half2 p0 = *(__half2*)&rr.x;
            __half2 p1 = *(__half2*)&rr.y;
            float2 f0 = __half22float2(p0);
            float2 f1 = __half22float2(p1);
            v.x += f0.x; v.y += f0.y; v.z += f1.x; v.w += f1.y;
            *(float4*)(outs + slot) = v;
        }
    }
}

// ---------------------------------------------------------------------------
// Per-graph mean-pool + final linear. batch SORTED -> contiguous ranges.
// Input sliced-32: thread t owns slice t>>5, channel t&31.
__global__ __launch_bounds__(128) void k_poolfinal(
    const float* __restrict__ Hs, const int* __restrict__ batch,
    const float* __restrict__ Wf, const float* __restrict__ bf,
    float* __restrict__ out, int n) {
    int g = blockIdx.x;
    int t = threadIdx.x;
    int lo = 0, hi = n;
    while (lo < hi) { int m = (lo + hi) >> 1; if (batch[m] < g) lo = m + 1; else hi = m; }
    int start = lo;
    lo = 0; hi = n;
    while (lo < hi) { int m = (lo + hi) >> 1; if (batch[m] < g + 1) lo = m + 1; else hi = m; }
    int end = lo;

    const float* base = Hs + (size_t)(t >> 5) * ((size_t)n * 32) + (t & 31);
    float acc = 0.f;
    for (int i = start; i < end; ++i) acc += base[(size_t)i * 32];
    float v = acc * Wf[t];

    __shared__ float red[128];
    red[t] = v;
    __syncthreads();
    for (int s = 64; s > 0; s >>= 1) {
        if (t < s) red[t] += red[t + s];
        __syncthreads();
    }
    if (t == 0) out[g] = red[0] / fmaxf((float)(end - start), 1.f) + bf[0];
}

// ---------------------------------------------------------------------------
extern "C" void kernel_launch(void* const* d_in, const int* in_sizes, int n_in,
                              void* d_out, int out_size, void* d_ws, size_t ws_size,
                              hipStream_t stream) {
    const float* x     = (const float*)d_in[0];
    const int*   ei    = (const int*)d_in[1];
    const int*   src   = ei;
    const int*   dst   = ei + N_EDGES;
    const float* w     = (const float*)d_in[2];
    const int*   batch = (const int*)d_in[3];
    const float* W1 = (const float*)d_in[4];
    const float* b1 = (const float*)d_in[5];
    const float* W2 = (const float*)d_in[6];
    const float* b2 = (const float*)d_in[7];
    const float* W3 = (const float*)d_in[8];
    const float* b3 = (const float*)d_in[9];
    const float* Wf = (const float*)d_in[10];
    const float* bf = (const float*)d_in[11];
    const float* g1 = (const float*)d_in[12];
    const float* be1 = (const float*)d_in[13];
    const float* m1 = (const float*)d_in[14];
    const float* v1 = (const float*)d_in[15];
    const float* g2 = (const float*)d_in[16];
    const float* be2 = (const float*)d_in[17];
    const float* m2 = (const float*)d_in[18];
    const float* v2 = (const float*)d_in[19];
    const float* g3 = (const float*)d_in[20];
    const float* be3 = (const float*)d_in[21];
    const float* m3 = (const float*)d_in[22];
    const float* v3 = (const float*)d_in[23];

    float* out = (float*)d_out;

    // Workspace layout
    float* ws    = (float*)d_ws;
    float* buf2  = ws;                                    // N*128 fp32: agg2 then agg3s
    float* agg2  = buf2;                                  //   (mmT128 writes out3 in-place)
    unsigned* csr = (unsigned*)(buf2 + (size_t)N_NODES * 128); // E uint
    unsigned long long* packed = (unsigned long long*)(csr + N_EDGES); // N ull
    int*   seq   = (int*)(packed + N_NODES);              // E
    float* dinv  = (float*)(seq + N_EDGES);               // N
    float* aggx  = dinv + N_NODES;                        // N
    float* kA1   = aggx + N_NODES;                        // 64
    float* kB1   = kA1 + 64;                              // 64
    float* kA2   = kB1 + 64;                              // 128
    float* kB2   = kA2 + 128;                             // 128
    float* kA3   = kB2 + 128;                             // 128
    float* kB3   = kA3 + 128;                             // 128
    int*   offs  = (int*)(kB3 + 128);                     // N+1
    int*   bsum  = offs + N_NODES + 1;                    // SCAN_NB
    int*   bpre  = bsum + SCAN_NB;                        // SCAN_NB
    __half* out2h = (__half*)(bpre + SCAN_NB + 2);        // N*128 fp16 (12.8 MB)

    const int BS = 256;
    auto nb = [](long n) { return (int)((n + 255) / 256); };

    hipMemsetAsync(packed, 0, N_NODES * sizeof(unsigned long long), stream);

    // --- CSR build + degree norm ---
    k_degcnt<<<nb(N_EDGES), BS, 0, stream>>>(dst, w, packed, seq, N_EDGES);
    k_scan1<<<SCAN_NB, 256, 0, stream>>>(packed, bsum, N_NODES);
    k_scan2<<<1, 256, 0, stream>>>(bsum, bpre, SCAN_NB);
    k_scan3<<<SCAN_NB, 256, 0, stream>>>(packed, bpre, offs, dinv, N_NODES);
    k_fill<<<nb(N_EDGES), BS, 0, stream>>>(src, dst, w, dinv, offs, seq, csr, N_EDGES);
    k_bnprep_all<<<1, 320, 0, stream>>>(W1, b1, g1, be1, m1, v1, b2, g2, be2, m2, v2,
                                        b3, g3, be3, m3, v3, kA1, kB1, kA2, kB2, kA3, kB3);

    // --- Layer 1 aggregate (scalar) ---
    k_aggx<<<nb(N_NODES), BS, 0, stream>>>(offs, csr, x, dinv, aggx, N_NODES);

    // --- Layer 2: fused L1-matmul + aggregate, then 64->128 matmul -> fp16 (sliced-32) ---
    k_gather2F<<<nb((long)N_NODES * 16), BS, 0, stream>>>(
        offs, csr, aggx, dinv, kA1, kB1, agg2, N_NODES);
    k_mmT<64, 1, 0><<<(N_NODES + 31) / 32, BS, 0, stream>>>(
        agg2, W2, kA2, kB2, nullptr, nullptr, out2h, N_NODES);

    // --- Layer 3: 4-slice gather from fp16 table (64B rows), matmul + relu + res ---
    k_gatherS16<<<4 * ((N_NODES + 31) / 32), BS, 0, stream>>>(
        offs, csr, out2h, dinv, buf2, N_NODES);
    k_mmT<128, 4, 1><<<(N_NODES + 31) / 32, BS, 0, stream>>>(
        buf2, W3, kA3, kB3, out2h, buf2, nullptr, N_NODES);

    // --- per-graph mean pool + final linear ---
    k_poolfinal<<<N_GRAPHS, 128, 0, stream>>>(buf2, batch, Wf, bf, out, N_NODES);
}

// Round 21
// 285.698 us; speedup vs baseline: 1.0964x; 1.0964x over previous
//
#include <hip/hip_runtime.h>
#include <hip/hip_fp16.h>

#define N_NODES  50000
#define N_EDGES  640000
#define N_GRAPHS 500
static constexpr float BN_EPS = 1e-5f;
#define SCAN_NB ((N_NODES + 255) / 256)   // 196 blocks
static constexpr float FIX = 16777216.0f;       // 2^24
static constexpr float FIXINV = 5.9604644775390625e-8f;  // 2^-24
static constexpr float Q16 = 65535.0f;
static constexpr float Q16INV = 1.0f / 65535.0f;

// csr entry: (src<<16) | round(norm*65535). src<50000<2^16; norm<1.
__device__ __forceinline__ float dec_nm(unsigned e) {
    return (float)(e & 0xFFFFu) * Q16INV;
}

// ---------------------------------------------------------------------------
// Packed degree/count: one 64-bit atomic per edge; old value -> seq[] rank.
__global__ void k_degcnt(const int* __restrict__ dst, const float* __restrict__ w,
                         unsigned long long* __restrict__ packed,
                         int* __restrict__ seq, int E) {
    int i = blockIdx.x * blockDim.x + threadIdx.x;
    if (i < E) {
        int d = dst[i];
        unsigned uf = (unsigned)(w[i] * FIX + 0.5f);
        unsigned long long old =
            atomicAdd(&packed[d], (1ULL << 32) | (unsigned long long)uf);
        seq[i] = (int)(old >> 32);
    }
}

// --- 3-phase hierarchical exclusive scan of counts (packed hi32) -> offs ---
__global__ void k_scan1(const unsigned long long* __restrict__ packed,
                        int* __restrict__ bsum, int n) {
    __shared__ int red[256];
    int i = blockIdx.x * 256 + threadIdx.x;
    red[threadIdx.x] = (i < n) ? (int)(packed[i] >> 32) : 0;
    __syncthreads();
    for (int off = 128; off > 0; off >>= 1) {
        if (threadIdx.x < off) red[threadIdx.x] += red[threadIdx.x + off];
        __syncthreads();
    }
    if (threadIdx.x == 0) bsum[blockIdx.x] = red[0];
}

__global__ void k_scan2(const int* __restrict__ bsum, int* __restrict__ bpre, int nb) {
    __shared__ int part[256];
    int t = threadIdx.x;
    part[t] = (t < nb) ? bsum[t] : 0;
    __syncthreads();
    for (int off = 1; off < 256; off <<= 1) {
        int v = (t >= off) ? part[t - off] : 0;
        __syncthreads();
        part[t] += v;
        __syncthreads();
    }
    if (t < nb) bpre[t] = (t == 0) ? 0 : part[t - 1];
}

// scan3 + dinv fused (same N-grid).
__global__ void k_scan3(const unsigned long long* __restrict__ packed,
                        const int* __restrict__ bpre, int* __restrict__ offs,
                        float* __restrict__ dinv, int n) {
    __shared__ int part[256];
    int i = blockIdx.x * 256 + threadIdx.x;
    int t = threadIdx.x;
    unsigned long long pk = (i < n) ? packed[i] : 0ULL;
    int v = (int)(pk >> 32);
    part[t] = v;
    __syncthreads();
    for (int off = 1; off < 256; off <<= 1) {
        int u = (t >= off) ? part[t - off] : 0;
        __syncthreads();
        part[t] += u;
        __syncthreads();
    }
    int excl = bpre[blockIdx.x] + part[t] - v;
    if (i < n) {
        offs[i] = excl;
        float wdeg = (float)(unsigned)(pk & 0xFFFFFFFFu) * FIXINV;
        dinv[i] = rsqrtf(wdeg + 1.0f);
    }
    if (i == n - 1) offs[n] = N_EDGES;
}

// Atomic-free CSR fill: pos = offs[dst] + seq[e]. 4-byte packed entry.
__global__ void k_fill(const int* __restrict__ src, const int* __restrict__ dst,
                       const float* __restrict__ w, const float* __restrict__ dinv,
                       const int* __restrict__ offs, const int* __restrict__ seq,
                       unsigned* __restrict__ csr, int E) {
    int e = blockIdx.x * blockDim.x + threadIdx.x;
    if (e < E) {
        int s = src[e], d = dst[e];
        int pos = offs[d] + seq[e];
        float nm = dinv[s] * w[e] * dinv[d];
        unsigned q = (unsigned)(nm * Q16 + 0.5f);
        q = (q > 65535u) ? 65535u : q;
        csr[pos] = ((unsigned)s << 16) | q;
    }
}

// Fold bias+BN into per-channel affine. Layer1 additionally folds W1 (rank-1).
__global__ void k_bnprep_all(
    const float* W1,
    const float* b1, const float* g1, const float* be1, const float* m1, const float* v1,
    const float* b2, const float* g2, const float* be2, const float* m2, const float* v2,
    const float* b3, const float* g3, const float* be3, const float* m3, const float* v3,
    float* kA1, float* kB1, float* kA2, float* kB2, float* kA3, float* kB3) {
    int t = threadIdx.x;
    if (t < 64) {
        float s = g1[t] * rsqrtf(v1[t] + BN_EPS);
        kA1[t] = W1[t] * s;
        kB1[t] = (b1[t] - m1[t]) * s + be1[t];
    } else if (t < 192) {
        int c = t - 64;
        float s = g2[c] * rsqrtf(v2[c] + BN_EPS);
        kA2[c] = s; kB2[c] = (b2[c] - m2[c]) * s + be2[c];
    } else if (t < 320) {
        int c = t - 192;
        float s = g3[c] * rsqrtf(v3[c] + BN_EPS);
        kA3[c] = s; kB3[c] = (b3[c] - m3[c]) * s + be3[c];
    }
}

// Layer-1 scalar aggregation (id order; 4-edge unrolled).
__global__ void k_aggx(const int* __restrict__ offs, const unsigned* __restrict__ csr,
                       const float* __restrict__ x, const float* __restrict__ dinv,
                       float* __restrict__ aggx, int n) {
    int i = blockIdx.x * blockDim.x + threadIdx.x;
    if (i >= n) return;
    float acc = 0.f;
    int e0 = offs[i], e1 = offs[i + 1];
    int j = e0;
    for (; j + 3 < e1; j += 4) {
        unsigned ea = csr[j];
        unsigned eb = csr[j + 1];
        unsigned ec = csr[j + 2];
        unsigned ed = csr[j + 3];
        acc += x[ea >> 16] * dec_nm(ea) + x[eb >> 16] * dec_nm(eb)
             + x[ec >> 16] * dec_nm(ec) + x[ed >> 16] * dec_nm(ed);
    }
    for (; j < e1; ++j) {
        unsigned e = csr[j];
        acc += x[e >> 16] * dec_nm(e);
    }
    float di = dinv[i];
    aggx[i] = acc + x[i] * di * di;
}

// ---------------------------------------------------------------------------
// Fused layer-1-matmul + layer-2 aggregation. 16 threads/node, 4 ch each.
__global__ void k_gather2F(const int* __restrict__ offs, const unsigned* __restrict__ csr,
                           const float* __restrict__ aggx, const float* __restrict__ dinv,
                           const float* __restrict__ kA1, const float* __restrict__ kB1,
                           float* __restrict__ agg2, int n) {
    int gid = blockIdx.x * blockDim.x + threadIdx.x;
    int node = gid >> 4;
    if (node >= n) return;
    int c4 = (gid & 15) * 4;
    float4 wa = *(const float4*)(kA1 + c4);
    float4 wb = *(const float4*)(kB1 + c4);
    float4 acc = {0.f, 0.f, 0.f, 0.f};
    int e0 = offs[node], e1 = offs[node + 1];
    int j = e0;
    for (; j + 3 < e1; j += 4) {
        unsigned ea = csr[j];
        unsigned eb = csr[j + 1];
        unsigned ec = csr[j + 2];
        unsigned ed = csr[j + 3];
        float aa = aggx[ea >> 16];
        float ab = aggx[eb >> 16];
        float ac = aggx[ec >> 16];
        float ad = aggx[ed >> 16];
        float nma = dec_nm(ea);
        float nmb = dec_nm(eb);
        float nmc = dec_nm(ec);
        float nmd = dec_nm(ed);
        acc.x += nma * fmaxf(aa * wa.x + wb.x, 0.f) + nmb * fmaxf(ab * wa.x + wb.x, 0.f)
               + nmc * fmaxf(ac * wa.x + wb.x, 0.f) + nmd * fmaxf(ad * wa.x + wb.x, 0.f);
        acc.y += nma * fmaxf(aa * wa.y + wb.y, 0.f) + nmb * fmaxf(ab * wa.y + wb.y, 0.f)
               + nmc * fmaxf(ac * wa.y + wb.y, 0.f) + nmd * fmaxf(ad * wa.y + wb.y, 0.f);
        acc.z += nma * fmaxf(aa * wa.z + wb.z, 0.f) + nmb * fmaxf(ab * wa.z + wb.z, 0.f)
               + nmc * fmaxf(ac * wa.z + wb.z, 0.f) + nmd * fmaxf(ad * wa.z + wb.z, 0.f);
        acc.w += nma * fmaxf(aa * wa.w + wb.w, 0.f) + nmb * fmaxf(ab * wa.w + wb.w, 0.f)
               + nmc * fmaxf(ac * wa.w + wb.w, 0.f) + nmd * fmaxf(ad * wa.w + wb.w, 0.f);
    }
    for (; j < e1; ++j) {
        unsigned e = csr[j];
        float a = aggx[e >> 16];
        float nm = dec_nm(e);
        acc.x += nm * fmaxf(a * wa.x + wb.x, 0.f);
        acc.y += nm * fmaxf(a * wa.y + wb.y, 0.f);
        acc.z += nm * fmaxf(a * wa.z + wb.z, 0.f);
        acc.w += nm * fmaxf(a * wa.w + wb.w, 0.f);
    }
    float di = dinv[node];
    float d2 = di * di;
    float a = aggx[node];
    acc.x += d2 * fmaxf(a * wa.x + wb.x, 0.f);
    acc.y += d2 * fmaxf(a * wa.y + wb.y, 0.f);
    acc.z += d2 * fmaxf(a * wa.z + wb.z, 0.f);
    acc.w += d2 * fmaxf(a * wa.w + wb.w, 0.f);
    *(float4*)(agg2 + (size_t)node * 64 + c4) = acc;
}

// ---------------------------------------------------------------------------
// Channel-sliced gather (layer 3) from the FP16 layer-2 output (sliced-16):
// slice table 1.6MB (L2-resident), 4 thr/node, 8B/thread, fp32 accumulation,
// 8-edge unroll. (r20's sliced-32 variant regressed — reverted.)
__global__ void k_gatherS16(const int* __restrict__ offs, const unsigned* __restrict__ csr,
                            const __half* __restrict__ Hh, const float* __restrict__ dinv,
                            float* __restrict__ aggs, int n) {
    int slice = blockIdx.x & 7;
    int node = (blockIdx.x >> 3) * 64 + threadIdx.x / 4;
    if (node >= n) return;
    int cq = (threadIdx.x % 4) * 4;
    const __half* Hb = Hh + (size_t)slice * ((size_t)n * 16);
    float4 acc = {0.f, 0.f, 0.f, 0.f};
    int e0 = offs[node], e1 = offs[node + 1];
    int j = e0;
#define GS16_LOAD(ev, rawv) uint2 rawv = *(const uint2*)(Hb + (size_t)((ev) >> 16) * 16 + cq)
#define GS16_ACC(rawv, nmv) { \
        __half2 p0 = *(__half2*)&rawv.x; \
        __half2 p1 = *(__half2*)&rawv.y; \
        float2 f0 = __half22float2(p0); \
        float2 f1 = __half22float2(p1); \
        acc.x += f0.x * nmv; acc.y += f0.y * nmv; \
        acc.z += f1.x * nmv; acc.w += f1.y * nmv; }
    for (; j + 7 < e1; j += 8) {
        unsigned e_0 = csr[j];
        unsigned e_1 = csr[j + 1];
        unsigned e_2 = csr[j + 2];
        unsigned e_3 = csr[j + 3];
        unsigned e_4 = csr[j + 4];
        unsigned e_5 = csr[j + 5];
        unsigned e_6 = csr[j + 6];
        unsigned e_7 = csr[j + 7];
        GS16_LOAD(e_0, r0); GS16_LOAD(e_1, r1); GS16_LOAD(e_2, r2); GS16_LOAD(e_3, r3);
        GS16_LOAD(e_4, r4); GS16_LOAD(e_5, r5); GS16_LOAD(e_6, r6); GS16_LOAD(e_7, r7);
        GS16_ACC(r0, dec_nm(e_0)); GS16_ACC(r1, dec_nm(e_1));
        GS16_ACC(r2, dec_nm(e_2)); GS16_ACC(r3, dec_nm(e_3));
        GS16_ACC(r4, dec_nm(e_4)); GS16_ACC(r5, dec_nm(e_5));
        GS16_ACC(r6, dec_nm(e_6)); GS16_ACC(r7, dec_nm(e_7));
    }
    for (; j < e1; ++j) {
        unsigned e = csr[j];
        GS16_LOAD(e, rr);
        GS16_ACC(rr, dec_nm(e));
    }
    {
        float di = dinv[node];
        float d2 = di * di;
        GS16_LOAD((unsigned)node << 16, rs);
        GS16_ACC(rs, d2);
    }
#undef GS16_LOAD
#undef GS16_ACC
    *(float4*)(aggs + (size_t)slice * ((size_t)n * 16) + (size_t)node * 16 + cq) = acc;
}

// ---------------------------------------------------------------------------
// Register-tiled matmul: 32 nodes/block, x-tile AND W staged in LDS.
// k4/p loops pinned rolled (#pragma unroll 1) — r6/r8 spilled at 256 VGPR.
// Sliced-16 slot layout. MODE 0 (layer 2): write fp16 table only.
// MODE 1 (layer 3): residual from fp16 table; write fp32 IN-PLACE into Xs.
template <int K, int S, int MODE>
__global__ __launch_bounds__(256) void k_mmT(
    const float* __restrict__ Xs, const float* __restrict__ W,
    const float* __restrict__ kA, const float* __restrict__ kB,
    const __half* __restrict__ resh, float* __restrict__ outs,
    __half* __restrict__ outh, int n) {
    constexpr int CS = K / S;
    constexpr int KP = K + 4;
    constexpr int KH = 64;
    constexpr int NPASS = K / KH;
    __shared__ float xl[32 * KP];
    __shared__ float wl[KH * 128];
    int base = blockIdx.x * 32;
    int tid = threadIdx.x;
    constexpr int TOT4 = 32 * K / 4;
    constexpr int SL4 = 32 * CS / 4;
    for (int i = tid; i < TOT4; i += 256) {
        int slice = i / SL4;
        int rem = i - slice * SL4;
        int nl = rem / (CS / 4);
        int off4 = (rem % (CS / 4)) * 4;
        int node = base + nl;
        float4 v = {0.f, 0.f, 0.f, 0.f};
        if (node < n)
            v = *(const float4*)(Xs + (size_t)slice * ((size_t)n * CS) + (size_t)node * CS + off4);
        *(float4*)(&xl[nl * KP + slice * CS + off4]) = v;
    }

    int ct = tid & 31;
    int ng = tid >> 5;
    int c4 = ct * 4;
    float4 acc[4];
#pragma unroll
    for (int i = 0; i < 4; ++i) acc[i] = make_float4(0.f, 0.f, 0.f, 0.f);

#pragma unroll 1
    for (int p = 0; p < NPASS; ++p) {
        if (p > 0) __syncthreads();
        {
            const float4* Wsrc = (const float4*)(W + (size_t)p * KH * 128);
            float4* wl4 = (float4*)wl;
#pragma unroll 1
            for (int i = tid; i < KH * 32; i += 256) wl4[i] = Wsrc[i];
        }
        __syncthreads();

#pragma unroll 1
        for (int k4 = 0; k4 < KH / 4; ++k4) {
            float4 wv0 = *(const float4*)(&wl[(k4 * 4 + 0) * 128 + c4]);
            float4 wv1 = *(const float4*)(&wl[(k4 * 4 + 1) * 128 + c4]);
            float4 wv2 = *(const float4*)(&wl[(k4 * 4 + 2) * 128 + c4]);
            float4 wv3 = *(const float4*)(&wl[(k4 * 4 + 3) * 128 + c4]);
#pragma unroll
            for (int i = 0; i < 4; ++i) {
                float4 xv = *(const float4*)(&xl[(ng * 4 + i) * KP + p * KH + k4 * 4]);
                acc[i].x += xv.x * wv0.x; acc[i].y += xv.x * wv0.y;
                acc[i].z += xv.x * wv0.z; acc[i].w += xv.x * wv0.w;
                acc[i].x += xv.y * wv1.x; acc[i].y += xv.y * wv1.y;
                acc[i].z += xv.y * wv1.z; acc[i].w += xv.y * wv1.w;
                acc[i].x += xv.z * wv2.x; acc[i].y += xv.z * wv2.y;
                acc[i].z += xv.z * wv2.z; acc[i].w += xv.z * wv2.w;
                acc[i].x += xv.w * wv3.x; acc[i].y += xv.w * wv3.y;
                acc[i].z += xv.w * wv3.z; acc[i].w += xv.w * wv3.w;
            }
        }
    }

    float4 ka = *(const float4*)(kA + c4);
    float4 kb = *(const float4*)(kB + c4);
#pragma unroll
    for (int i = 0; i < 4; ++i) {
        int node = base + ng * 4 + i;
        if (node >= n) continue;
        float4 a = acc[i];
        float4 v;
        v.x = fmaxf(a.x * ka.x + kb.x, 0.f);
        v.y = fmaxf(a.y * ka.y + kb.y, 0.f);
        v.z = fmaxf(a.z * ka.z + kb.z, 0.f);
        v.w = fmaxf(a.w * ka.w + kb.w, 0.f);
        size_t slot = (size_t)(c4 >> 4) * ((size_t)n * 16) + (size_t)node * 16 + (c4 & 15);
        if (MODE == 0) {
            __half2 h01 = __floats2half2_rn(v.x, v.y);
            __half2 h23 = __floats2half2_rn(v.z, v.w);
            uint2 r;
            r.x = *(unsigned*)&h01;
            r.y = *(unsigned*)&h23;
            *(uint2*)(outh + slot) = r;
        } else {
            uint2 rr = *(const uint2*)(resh + slot);
            __half2 p0 = *(__half2*)&rr.x;
            __half2 p1 = *(__half2*)&rr.y;
            float2 f0 = __half22float2(p0);
            float2 f1 = __half22float2(p1);
            v.x += f0.x; v.y += f0.y; v.z += f1.x; v.w += f1.y;
            *(float4*)(outs + slot) = v;
        }
    }
}

// ---------------------------------------------------------------------------
// Per-graph mean-pool + final linear. batch SORTED -> contiguous ranges.
// 1024 threads: thread t owns channel t&127, sub-lane t>>7 (8-way node split)
// — r20 counters showed the 128-thread version latency-bound at 45µs, 7.6% occ.
__global__ __launch_bounds__(1024) void k_poolfinal(
    const float* __restrict__ Hs, const int* __restrict__ batch,
    const float* __restrict__ Wf, const float* __restrict__ bf,
    float* __restrict__ out, int n) {
    int g = blockIdx.x;
    int t = threadIdx.x;
    int ch = t & 127;
    int sub = t >> 7;           // 0..7
    int lo = 0, hi = n;
    while (lo < hi) { int m = (lo + hi) >> 1; if (batch[m] < g) lo = m + 1; else hi = m; }
    int start = lo;
    lo = 0; hi = n;
    while (lo < hi) { int m = (lo + hi) >> 1; if (batch[m] < g + 1) lo = m + 1; else hi = m; }
    int end = lo;

    const float* base = Hs + (size_t)(ch >> 4) * ((size_t)n * 16) + (ch & 15);
    float acc = 0.f;
    for (int i = start + sub; i < end; i += 8) acc += base[(size_t)i * 16];

    __shared__ float red[1024];
    red[t] = acc;
    __syncthreads();
    // reduce over sub (1024 -> 128)
    for (int s = 512; s >= 128; s >>= 1) {
        if (t < s) red[t] += red[t + s];
        __syncthreads();
    }
    // channel dot with Wf, then 128 -> 1
    if (t < 128) red[t] *= Wf[t];
    __syncthreads();
    for (int s = 64; s > 0; s >>= 1) {
        if (t < s) red[t] += red[t + s];
        __syncthreads();
    }
    if (t == 0) out[g] = red[0] / fmaxf((float)(end - start), 1.f) + bf[0];
}

// ---------------------------------------------------------------------------
extern "C" void kernel_launch(void* const* d_in, const int* in_sizes, int n_in,
                              void* d_out, int out_size, void* d_ws, size_t ws_size,
                              hipStream_t stream) {
    const float* x     = (const float*)d_in[0];
    const int*   ei    = (const int*)d_in[1];
    const int*   src   = ei;
    const int*   dst   = ei + N_EDGES;
    const float* w     = (const float*)d_in[2];
    const int*   batch = (const int*)d_in[3];
    const float* W1 = (const float*)d_in[4];
    const float* b1 = (const float*)d_in[5];
    const float* W2 = (const float*)d_in[6];
    const float* b2 = (const float*)d_in[7];
    const float* W3 = (const float*)d_in[8];
    const float* b3 = (const float*)d_in[9];
    const float* Wf = (const float*)d_in[10];
    const float* bf = (const float*)d_in[11];
    const float* g1 = (const float*)d_in[12];
    const float* be1 = (const float*)d_in[13];
    const float* m1 = (const float*)d_in[14];
    const float* v1 = (const float*)d_in[15];
    const float* g2 = (const float*)d_in[16];
    const float* be2 = (const float*)d_in[17];
    const float* m2 = (const float*)d_in[18];
    const float* v2 = (const float*)d_in[19];
    const float* g3 = (const float*)d_in[20];
    const float* be3 = (const float*)d_in[21];
    const float* m3 = (const float*)d_in[22];
    const float* v3 = (const float*)d_in[23];

    float* out = (float*)d_out;

    // Workspace layout
    float* ws    = (float*)d_ws;
    float* buf2  = ws;                                    // N*128 fp32: agg2 then agg3s
    float* agg2  = buf2;                                  //   (mmT128 writes out3 in-place)
    unsigned* csr = (unsigned*)(buf2 + (size_t)N_NODES * 128); // E uint
    unsigned long long* packed = (unsigned long long*)(csr + N_EDGES); // N ull
    int*   seq   = (int*)(packed + N_NODES);              // E
    float* dinv  = (float*)(seq + N_EDGES);               // N
    float* aggx  = dinv + N_NODES;                        // N
    float* kA1   = aggx + N_NODES;                        // 64
    float* kB1   = kA1 + 64;                              // 64
    float* kA2   = kB1 + 64;                              // 128
    float* kB2   = kA2 + 128;                             // 128
    float* kA3   = kB2 + 128;                             // 128
    float* kB3   = kA3 + 128;                             // 128
    int*   offs  = (int*)(kB3 + 128);                     // N+1
    int*   bsum  = offs + N_NODES + 1;                    // SCAN_NB
    int*   bpre  = bsum + SCAN_NB;                        // SCAN_NB
    __half* out2h = (__half*)(bpre + SCAN_NB + 2);        // N*128 fp16 (12.8 MB)

    const int BS = 256;
    auto nb = [](long n) { return (int)((n + 255) / 256); };

    hipMemsetAsync(packed, 0, N_NODES * sizeof(unsigned long long), stream);

    // --- CSR build + degree norm ---
    k_degcnt<<<nb(N_EDGES), BS, 0, stream>>>(dst, w, packed, seq, N_EDGES);
    k_scan1<<<SCAN_NB, 256, 0, stream>>>(packed, bsum, N_NODES);
    k_scan2<<<1, 256, 0, stream>>>(bsum, bpre, SCAN_NB);
    k_scan3<<<SCAN_NB, 256, 0, stream>>>(packed, bpre, offs, dinv, N_NODES);
    k_fill<<<nb(N_EDGES), BS, 0, stream>>>(src, dst, w, dinv, offs, seq, csr, N_EDGES);
    k_bnprep_all<<<1, 320, 0, stream>>>(W1, b1, g1, be1, m1, v1, b2, g2, be2, m2, v2,
                                        b3, g3, be3, m3, v3, kA1, kB1, kA2, kB2, kA3, kB3);

    // --- Layer 1 aggregate (scalar) ---
    k_aggx<<<nb(N_NODES), BS, 0, stream>>>(offs, csr, x, dinv, aggx, N_NODES);

    // --- Layer 2: fused L1-matmul + aggregate, then 64->128 matmul -> fp16 only ---
    k_gather2F<<<nb((long)N_NODES * 16), BS, 0, stream>>>(
        offs, csr, aggx, dinv, kA1, kB1, agg2, N_NODES);
    k_mmT<64, 1, 0><<<(N_NODES + 31) / 32, BS, 0, stream>>>(
        agg2, W2, kA2, kB2, nullptr, nullptr, out2h, N_NODES);

    // --- Layer 3: sliced aggregate from fp16 table, matmul + relu + fp16 res ---
    k_gatherS16<<<8 * ((N_NODES + 63) / 64), BS, 0, stream>>>(
        offs, csr, out2h, dinv, buf2, N_NODES);
    k_mmT<128, 8, 1><<<(N_NODES + 31) / 32, BS, 0, stream>>>(
        buf2, W3, kA3, kB3, out2h, buf2, nullptr, N_NODES);

    // --- per-graph mean pool + final linear (1024-thread, 8-way node split) ---
    k_poolfinal<<<N_GRAPHS, 1024, 0, stream>>>(buf2, batch, Wf, bf, out, N_NODES);
}

// Round 22
// 280.593 us; speedup vs baseline: 1.1164x; 1.0182x over previous
//
#include <hip/hip_runtime.h>
#include <hip/hip_fp16.h>

#define N_NODES  50000
#define N_EDGES  640000
#define N_GRAPHS 500
static constexpr float BN_EPS = 1e-5f;
#define SCAN_NB ((N_NODES + 255) / 256)   // 196 blocks
static constexpr float FIX = 16777216.0f;       // 2^24
static constexpr float FIXINV = 5.9604644775390625e-8f;  // 2^-24
static constexpr float Q16 = 65535.0f;
static constexpr float Q16INV = 1.0f / 65535.0f;

// csr entry: (src<<16) | round(norm*65535). src<50000<2^16; norm<1.
__device__ __forceinline__ float dec_nm(unsigned e) {
    return (float)(e & 0xFFFFu) * Q16INV;
}

// ---------------------------------------------------------------------------
// Packed degree/count: one 64-bit atomic per edge; old value -> seq[] rank.
__global__ void k_degcnt(const int* __restrict__ dst, const float* __restrict__ w,
                         unsigned long long* __restrict__ packed,
                         int* __restrict__ seq, int E) {
    int i = blockIdx.x * blockDim.x + threadIdx.x;
    if (i < E) {
        int d = dst[i];
        unsigned uf = (unsigned)(w[i] * FIX + 0.5f);
        unsigned long long old =
            atomicAdd(&packed[d], (1ULL << 32) | (unsigned long long)uf);
        seq[i] = (int)(old >> 32);
    }
}

// --- 3-phase hierarchical exclusive scan of counts (packed hi32) -> offs ---
__global__ void k_scan1(const unsigned long long* __restrict__ packed,
                        int* __restrict__ bsum, int n) {
    __shared__ int red[256];
    int i = blockIdx.x * 256 + threadIdx.x;
    red[threadIdx.x] = (i < n) ? (int)(packed[i] >> 32) : 0;
    __syncthreads();
    for (int off = 128; off > 0; off >>= 1) {
        if (threadIdx.x < off) red[threadIdx.x] += red[threadIdx.x + off];
        __syncthreads();
    }
    if (threadIdx.x == 0) bsum[blockIdx.x] = red[0];
}

// scan2 + bnprep fused (both tiny single-block jobs — saves one launch).
__global__ void k_scan2_bnprep(
    const int* __restrict__ bsum, int* __restrict__ bpre, int nb,
    const float* W1,
    const float* b1, const float* g1, const float* be1, const float* m1, const float* v1,
    const float* b2, const float* g2, const float* be2, const float* m2, const float* v2,
    const float* b3, const float* g3, const float* be3, const float* m3, const float* v3,
    float* kA1, float* kB1, float* kA2, float* kB2, float* kA3, float* kB3) {
    __shared__ int part[256];
    int t = threadIdx.x;
    if (t < 256) {
        part[t] = (t < nb) ? bsum[t] : 0;
    }
    __syncthreads();
    for (int off = 1; off < 256; off <<= 1) {
        int v = (t < 256 && t >= off) ? part[t - off] : 0;
        __syncthreads();
        if (t < 256) part[t] += v;
        __syncthreads();
    }
    if (t < nb) bpre[t] = (t == 0) ? 0 : part[t - 1];
    // bnprep (independent of scan)
    if (t < 64) {
        float s = g1[t] * rsqrtf(v1[t] + BN_EPS);
        kA1[t] = W1[t] * s;
        kB1[t] = (b1[t] - m1[t]) * s + be1[t];
    } else if (t < 192) {
        int c = t - 64;
        float s = g2[c] * rsqrtf(v2[c] + BN_EPS);
        kA2[c] = s; kB2[c] = (b2[c] - m2[c]) * s + be2[c];
    } else if (t < 320) {
        int c = t - 192;
        float s = g3[c] * rsqrtf(v3[c] + BN_EPS);
        kA3[c] = s; kB3[c] = (b3[c] - m3[c]) * s + be3[c];
    }
}

// scan3 + dinv fused (same N-grid).
__global__ void k_scan3(const unsigned long long* __restrict__ packed,
                        const int* __restrict__ bpre, int* __restrict__ offs,
                        float* __restrict__ dinv, int n) {
    __shared__ int part[256];
    int i = blockIdx.x * 256 + threadIdx.x;
    int t = threadIdx.x;
    unsigned long long pk = (i < n) ? packed[i] : 0ULL;
    int v = (int)(pk >> 32);
    part[t] = v;
    __syncthreads();
    for (int off = 1; off < 256; off <<= 1) {
        int u = (t >= off) ? part[t - off] : 0;
        __syncthreads();
        part[t] += u;
        __syncthreads();
    }
    int excl = bpre[blockIdx.x] + part[t] - v;
    if (i < n) {
        offs[i] = excl;
        float wdeg = (float)(unsigned)(pk & 0xFFFFFFFFu) * FIXINV;
        dinv[i] = rsqrtf(wdeg + 1.0f);
    }
    if (i == n - 1) offs[n] = N_EDGES;
}

// Atomic-free CSR fill: pos = offs[dst] + seq[e]. 4-byte packed entry.
__global__ void k_fill(const int* __restrict__ src, const int* __restrict__ dst,
                       const float* __restrict__ w, const float* __restrict__ dinv,
                       const int* __restrict__ offs, const int* __restrict__ seq,
                       unsigned* __restrict__ csr, int E) {
    int e = blockIdx.x * blockDim.x + threadIdx.x;
    if (e < E) {
        int s = src[e], d = dst[e];
        int pos = offs[d] + seq[e];
        float nm = dinv[s] * w[e] * dinv[d];
        unsigned q = (unsigned)(nm * Q16 + 0.5f);
        q = (q > 65535u) ? 65535u : q;
        csr[pos] = ((unsigned)s << 16) | q;
    }
}

// Layer-1 scalar aggregation (id order; 4-edge unrolled).
__global__ void k_aggx(const int* __restrict__ offs, const unsigned* __restrict__ csr,
                       const float* __restrict__ x, const float* __restrict__ dinv,
                       float* __restrict__ aggx, int n) {
    int i = blockIdx.x * blockDim.x + threadIdx.x;
    if (i >= n) return;
    float acc = 0.f;
    int e0 = offs[i], e1 = offs[i + 1];
    int j = e0;
    for (; j + 3 < e1; j += 4) {
        unsigned ea = csr[j];
        unsigned eb = csr[j + 1];
        unsigned ec = csr[j + 2];
        unsigned ed = csr[j + 3];
        acc += x[ea >> 16] * dec_nm(ea) + x[eb >> 16] * dec_nm(eb)
             + x[ec >> 16] * dec_nm(ec) + x[ed >> 16] * dec_nm(ed);
    }
    for (; j < e1; ++j) {
        unsigned e = csr[j];
        acc += x[e >> 16] * dec_nm(e);
    }
    float di = dinv[i];
    aggx[i] = acc + x[i] * di * di;
}

// ---------------------------------------------------------------------------
// Fused layer-1-matmul + layer-2 aggregation. 16 threads/node, 4 ch each.
// 8-edge unroll (r22: gather2F loads are lighter per edge than gatherS16's —
// deeper MLP should still pay here).
__global__ void k_gather2F(const int* __restrict__ offs, const unsigned* __restrict__ csr,
                           const float* __restrict__ aggx, const float* __restrict__ dinv,
                           const float* __restrict__ kA1, const float* __restrict__ kB1,
                           float* __restrict__ agg2, int n) {
    int gid = blockIdx.x * blockDim.x + threadIdx.x;
    int node = gid >> 4;
    if (node >= n) return;
    int c4 = (gid & 15) * 4;
    float4 wa = *(const float4*)(kA1 + c4);
    float4 wb = *(const float4*)(kB1 + c4);
    float4 acc = {0.f, 0.f, 0.f, 0.f};
    int e0 = offs[node], e1 = offs[node + 1];
    int j = e0;
#define G2F_ACC(av, nmv) { \
        acc.x += nmv * fmaxf(av * wa.x + wb.x, 0.f); \
        acc.y += nmv * fmaxf(av * wa.y + wb.y, 0.f); \
        acc.z += nmv * fmaxf(av * wa.z + wb.z, 0.f); \
        acc.w += nmv * fmaxf(av * wa.w + wb.w, 0.f); }
    for (; j + 7 < e1; j += 8) {
        unsigned e_0 = csr[j];
        unsigned e_1 = csr[j + 1];
        unsigned e_2 = csr[j + 2];
        unsigned e_3 = csr[j + 3];
        unsigned e_4 = csr[j + 4];
        unsigned e_5 = csr[j + 5];
        unsigned e_6 = csr[j + 6];
        unsigned e_7 = csr[j + 7];
        float a0 = aggx[e_0 >> 16];
        float a1 = aggx[e_1 >> 16];
        float a2 = aggx[e_2 >> 16];
        float a3 = aggx[e_3 >> 16];
        float a4 = aggx[e_4 >> 16];
        float a5 = aggx[e_5 >> 16];
        float a6 = aggx[e_6 >> 16];
        float a7 = aggx[e_7 >> 16];
        G2F_ACC(a0, dec_nm(e_0)); G2F_ACC(a1, dec_nm(e_1));
        G2F_ACC(a2, dec_nm(e_2)); G2F_ACC(a3, dec_nm(e_3));
        G2F_ACC(a4, dec_nm(e_4)); G2F_ACC(a5, dec_nm(e_5));
        G2F_ACC(a6, dec_nm(e_6)); G2F_ACC(a7, dec_nm(e_7));
    }
    for (; j < e1; ++j) {
        unsigned e = csr[j];
        float a = aggx[e >> 16];
        G2F_ACC(a, dec_nm(e));
    }
    {
        float di = dinv[node];
        float d2 = di * di;
        float a = aggx[node];
        G2F_ACC(a, d2);
    }
#undef G2F_ACC
    *(float4*)(agg2 + (size_t)node * 64 + c4) = acc;
}

// ---------------------------------------------------------------------------
// Channel-sliced gather (layer 3) from the FP16 layer-2 output (sliced-16):
// slice table 1.6MB (L2-resident), 4 thr/node, 8B/thread, fp32 accumulation,
// 8-edge unroll.
__global__ void k_gatherS16(const int* __restrict__ offs, const unsigned* __restrict__ csr,
                            const __half* __restrict__ Hh, const float* __restrict__ dinv,
                            float* __restrict__ aggs, int n) {
    int slice = blockIdx.x & 7;
    int node = (blockIdx.x >> 3) * 64 + threadIdx.x / 4;
    if (node >= n) return;
    int cq = (threadIdx.x % 4) * 4;
    const __half* Hb = Hh + (size_t)slice * ((size_t)n * 16);
    float4 acc = {0.f, 0.f, 0.f, 0.f};
    int e0 = offs[node], e1 = offs[node + 1];
    int j = e0;
#define GS16_LOAD(ev, rawv) uint2 rawv = *(const uint2*)(Hb + (size_t)((ev) >> 16) * 16 + cq)
#define GS16_ACC(rawv, nmv) { \
        __half2 p0 = *(__half2*)&rawv.x; \
        __half2 p1 = *(__half2*)&rawv.y; \
        float2 f0 = __half22float2(p0); \
        float2 f1 = __half22float2(p1); \
        acc.x += f0.x * nmv; acc.y += f0.y * nmv; \
        acc.z += f1.x * nmv; acc.w += f1.y * nmv; }
    for (; j + 7 < e1; j += 8) {
        unsigned e_0 = csr[j];
        unsigned e_1 = csr[j + 1];
        unsigned e_2 = csr[j + 2];
        unsigned e_3 = csr[j + 3];
        unsigned e_4 = csr[j + 4];
        unsigned e_5 = csr[j + 5];
        unsigned e_6 = csr[j + 6];
        unsigned e_7 = csr[j + 7];
        GS16_LOAD(e_0, r0); GS16_LOAD(e_1, r1); GS16_LOAD(e_2, r2); GS16_LOAD(e_3, r3);
        GS16_LOAD(e_4, r4); GS16_LOAD(e_5, r5); GS16_LOAD(e_6, r6); GS16_LOAD(e_7, r7);
        GS16_ACC(r0, dec_nm(e_0)); GS16_ACC(r1, dec_nm(e_1));
        GS16_ACC(r2, dec_nm(e_2)); GS16_ACC(r3, dec_nm(e_3));
        GS16_ACC(r4, dec_nm(e_4)); GS16_ACC(r5, dec_nm(e_5));
        GS16_ACC(r6, dec_nm(e_6)); GS16_ACC(r7, dec_nm(e_7));
    }
    for (; j < e1; ++j) {
        unsigned e = csr[j];
        GS16_LOAD(e, rr);
        GS16_ACC(rr, dec_nm(e));
    }
    {
        float di = dinv[node];
        float d2 = di * di;
        GS16_LOAD((unsigned)node << 16, rs);
        GS16_ACC(rs, d2);
    }
#undef GS16_LOAD
#undef GS16_ACC
    *(float4*)(aggs + (size_t)slice * ((size_t)n * 16) + (size_t)node * 16 + cq) = acc;
}

// ---------------------------------------------------------------------------
// Register-tiled matmul: 32 nodes/block, x-tile AND W staged in LDS.
// k4/p loops pinned rolled (#pragma unroll 1) — r6/r8 spilled at 256 VGPR.
// Sliced-16 slot layout. MODE 0 (layer 2): write fp16 table only.
// MODE 1 (layer 3): residual from fp16 table; write fp32 IN-PLACE into Xs.
template <int K, int S, int MODE>
__global__ __launch_bounds__(256) void k_mmT(
    const float* __restrict__ Xs, const float* __restrict__ W,
    const float* __restrict__ kA, const float* __restrict__ kB,
    const __half* __restrict__ resh, float* __restrict__ outs,
    __half* __restrict__ outh, int n) {
    constexpr int CS = K / S;
    constexpr int KP = K + 4;
    constexpr int KH = 64;
    constexpr int NPASS = K / KH;
    __shared__ float xl[32 * KP];
    __shared__ float wl[KH * 128];
    int base = blockIdx.x * 32;
    int tid = threadIdx.x;
    constexpr int TOT4 = 32 * K / 4;
    constexpr int SL4 = 32 * CS / 4;
    for (int i = tid; i < TOT4; i += 256) {
        int slice = i / SL4;
        int rem = i - slice * SL4;
        int nl = rem / (CS / 4);
        int off4 = (rem % (CS / 4)) * 4;
        int node = base + nl;
        float4 v = {0.f, 0.f, 0.f, 0.f};
        if (node < n)
            v = *(const float4*)(Xs + (size_t)slice * ((size_t)n * CS) + (size_t)node * CS + off4);
        *(float4*)(&xl[nl * KP + slice * CS + off4]) = v;
    }

    int ct = tid & 31;
    int ng = tid >> 5;
    int c4 = ct * 4;
    float4 acc[4];
#pragma unroll
    for (int i = 0; i < 4; ++i) acc[i] = make_float4(0.f, 0.f, 0.f, 0.f);

#pragma unroll 1
    for (int p = 0; p < NPASS; ++p) {
        if (p > 0) __syncthreads();
        {
            const float4* Wsrc = (const float4*)(W + (size_t)p * KH * 128);
            float4* wl4 = (float4*)wl;
#pragma unroll 1
            for (int i = tid; i < KH * 32; i += 256) wl4[i] = Wsrc[i];
        }
        __syncthreads();

#pragma unroll 1
        for (int k4 = 0; k4 < KH / 4; ++k4) {
            float4 wv0 = *(const float4*)(&wl[(k4 * 4 + 0) * 128 + c4]);
            float4 wv1 = *(const float4*)(&wl[(k4 * 4 + 1) * 128 + c4]);
            float4 wv2 = *(const float4*)(&wl[(k4 * 4 + 2) * 128 + c4]);
            float4 wv3 = *(const float4*)(&wl[(k4 * 4 + 3) * 128 + c4]);
#pragma unroll
            for (int i = 0; i < 4; ++i) {
                float4 xv = *(const float4*)(&xl[(ng * 4 + i) * KP + p * KH + k4 * 4]);
                acc[i].x += xv.x * wv0.x; acc[i].y += xv.x * wv0.y;
                acc[i].z += xv.x * wv0.z; acc[i].w += xv.x * wv0.w;
                acc[i].x += xv.y * wv1.x; acc[i].y += xv.y * wv1.y;
                acc[i].z += xv.y * wv1.z; acc[i].w += xv.y * wv1.w;
                acc[i].x += xv.z * wv2.x; acc[i].y += xv.z * wv2.y;
                acc[i].z += xv.z * wv2.z; acc[i].w += xv.z * wv2.w;
                acc[i].x += xv.w * wv3.x; acc[i].y += xv.w * wv3.y;
                acc[i].z += xv.w * wv3.z; acc[i].w += xv.w * wv3.w;
            }
        }
    }

    float4 ka = *(const float4*)(kA + c4);
    float4 kb = *(const float4*)(kB + c4);
#pragma unroll
    for (int i = 0; i < 4; ++i) {
        int node = base + ng * 4 + i;
        if (node >= n) continue;
        float4 a = acc[i];
        float4 v;
        v.x = fmaxf(a.x * ka.x + kb.x, 0.f);
        v.y = fmaxf(a.y * ka.y + kb.y, 0.f);
        v.z = fmaxf(a.z * ka.z + kb.z, 0.f);
        v.w = fmaxf(a.w * ka.w + kb.w, 0.f);
        size_t slot = (size_t)(c4 >> 4) * ((size_t)n * 16) + (size_t)node * 16 + (c4 & 15);
        if (MODE == 0) {
            __half2 h01 = __floats2half2_rn(v.x, v.y);
            __half2 h23 = __floats2half2_rn(v.z, v.w);
            uint2 r;
            r.x = *(unsigned*)&h01;
            r.y = *(unsigned*)&h23;
            *(uint2*)(outh + slot) = r;
        } else {
            uint2 rr = *(const uint2*)(resh + slot);
            __half2 p0 = *(__half2*)&rr.x;
            __half2 p1 = *(__half2*)&rr.y;
            float2 f0 = __half22float2(p0);
            float2 f1 = __half22float2(p1);
            v.x += f0.x; v.y += f0.y; v.z += f1.x; v.w += f1.y;
            *(float4*)(outs + slot) = v;
        }
    }
}

// ---------------------------------------------------------------------------
// Per-graph mean-pool + final linear. batch SORTED -> contiguous ranges.
// 1024 threads: thread t owns channel t&127, sub-lane t>>7 (8-way node split).
__global__ __launch_bounds__(1024) void k_poolfinal(
    const float* __restrict__ Hs, const int* __restrict__ batch,
    const float* __restrict__ Wf, const float* __restrict__ bf,
    float* __restrict__ out, int n) {
    int g = blockIdx.x;
    int t = threadIdx.x;
    int ch = t & 127;
    int sub = t >> 7;           // 0..7
    int lo = 0, hi = n;
    while (lo < hi) { int m = (lo + hi) >> 1; if (batch[m] < g) lo = m + 1; else hi = m; }
    int start = lo;
    lo = 0; hi = n;
    while (lo < hi) { int m = (lo + hi) >> 1; if (batch[m] < g + 1) lo = m + 1; else hi = m; }
    int end = lo;

    const float* base = Hs + (size_t)(ch >> 4) * ((size_t)n * 16) + (ch & 15);
    float acc = 0.f;
    for (int i = start + sub; i < end; i += 8) acc += base[(size_t)i * 16];

    __shared__ float red[1024];
    red[t] = acc;
    __syncthreads();
    for (int s = 512; s >= 128; s >>= 1) {
        if (t < s) red[t] += red[t + s];
        __syncthreads();
    }
    if (t < 128) red[t] *= Wf[t];
    __syncthreads();
    for (int s = 64; s > 0; s >>= 1) {
        if (t < s) red[t] += red[t + s];
        __syncthreads();
    }
    if (t == 0) out[g] = red[0] / fmaxf((float)(end - start), 1.f) + bf[0];
}

// ---------------------------------------------------------------------------
extern "C" void kernel_launch(void* const* d_in, const int* in_sizes, int n_in,
                              void* d_out, int out_size, void* d_ws, size_t ws_size,
                              hipStream_t stream) {
    const float* x     = (const float*)d_in[0];
    const int*   ei    = (const int*)d_in[1];
    const int*   src   = ei;
    const int*   dst   = ei + N_EDGES;
    const float* w     = (const float*)d_in[2];
    const int*   batch = (const int*)d_in[3];
    const float* W1 = (const float*)d_in[4];
    const float* b1 = (const float*)d_in[5];
    const float* W2 = (const float*)d_in[6];
    const float* b2 = (const float*)d_in[7];
    const float* W3 = (const float*)d_in[8];
    const float* b3 = (const float*)d_in[9];
    const float* Wf = (const float*)d_in[10];
    const float* bf = (const float*)d_in[11];
    const float* g1 = (const float*)d_in[12];
    const float* be1 = (const float*)d_in[13];
    const float* m1 = (const float*)d_in[14];
    const float* v1 = (const float*)d_in[15];
    const float* g2 = (const float*)d_in[16];
    const float* be2 = (const float*)d_in[17];
    const float* m2 = (const float*)d_in[18];
    const float* v2 = (const float*)d_in[19];
    const float* g3 = (const float*)d_in[20];
    const float* be3 = (const float*)d_in[21];
    const float* m3 = (const float*)d_in[22];
    const float* v3 = (const float*)d_in[23];

    float* out = (float*)d_out;

    // Workspace layout
    float* ws    = (float*)d_ws;
    float* buf2  = ws;                                    // N*128 fp32: agg2 then agg3s
    float* agg2  = buf2;                                  //   (mmT128 writes out3 in-place)
    unsigned* csr = (unsigned*)(buf2 + (size_t)N_NODES * 128); // E uint
    unsigned long long* packed = (unsigned long long*)(csr + N_EDGES); // N ull
    int*   seq   = (int*)(packed + N_NODES);              // E
    float* dinv  = (float*)(seq + N_EDGES);               // N
    float* aggx  = dinv + N_NODES;                        // N
    float* kA1   = aggx + N_NODES;                        // 64
    float* kB1   = kA1 + 64;                              // 64
    float* kA2   = kB1 + 64;                              // 128
    float* kB2   = kA2 + 128;                             // 128
    float* kA3   = kB2 + 128;                             // 128
    float* kB3   = kA3 + 128;                             // 128
    int*   offs  = (int*)(kB3 + 128);                     // N+1
    int*   bsum  = offs + N_NODES + 1;                    // SCAN_NB
    int*   bpre  = bsum + SCAN_NB;                        // SCAN_NB
    __half* out2h = (__half*)(bpre + SCAN_NB + 2);        // N*128 fp16 (12.8 MB)

    const int BS = 256;
    auto nb = [](long n) { return (int)((n + 255) / 256); };

    hipMemsetAsync(packed, 0, N_NODES * sizeof(unsigned long long), stream);

    // --- CSR build + degree norm ---
    k_degcnt<<<nb(N_EDGES), BS, 0, stream>>>(dst, w, packed, seq, N_EDGES);
    k_scan1<<<SCAN_NB, 256, 0, stream>>>(packed, bsum, N_NODES);
    k_scan2_bnprep<<<1, 320, 0, stream>>>(bsum, bpre, SCAN_NB,
                                          W1, b1, g1, be1, m1, v1, b2, g2, be2, m2, v2,
                                          b3, g3, be3, m3, v3,
                                          kA1, kB1, kA2, kB2, kA3, kB3);
    k_scan3<<<SCAN_NB, 256, 0, stream>>>(packed, bpre, offs, dinv, N_NODES);
    k_fill<<<nb(N_EDGES), BS, 0, stream>>>(src, dst, w, dinv, offs, seq, csr, N_EDGES);

    // --- Layer 1 aggregate (scalar) ---
    k_aggx<<<nb(N_NODES), BS, 0, stream>>>(offs, csr, x, dinv, aggx, N_NODES);

    // --- Layer 2: fused L1-matmul + aggregate (8-edge unroll), then matmul -> fp16 ---
    k_gather2F<<<nb((long)N_NODES * 16), BS, 0, stream>>>(
        offs, csr, aggx, dinv, kA1, kB1, agg2, N_NODES);
    k_mmT<64, 1, 0><<<(N_NODES + 31) / 32, BS, 0, stream>>>(
        agg2, W2, kA2, kB2, nullptr, nullptr, out2h, N_NODES);

    // --- Layer 3: sliced aggregate from fp16 table, matmul + relu + fp16 res ---
    k_gatherS16<<<8 * ((N_NODES + 63) / 64), BS, 0, stream>>>(
        offs, csr, out2h, dinv, buf2, N_NODES);
    k_mmT<128, 8, 1><<<(N_NODES + 31) / 32, BS, 0, stream>>>(
        buf2, W3, kA3, kB3, out2h, buf2, nullptr, N_NODES);

    // --- per-graph mean pool + final linear (1024-thread, 8-way node split) ---
    k_poolfinal<<<N_GRAPHS, 1024, 0, stream>>>(buf2, batch, Wf, bf, out, N_NODES);
}